// Round 5
// baseline (721.862 us; speedup 1.0000x reference)
//
#include <hip/hip_runtime.h>
#include <hip/hip_bf16.h>
#include <stdint.h>

// Problem: B=32, N=2048, D=512, K=64, G=16, M=B*N=65536, C=K+G=80
// Inputs fp32; OUTPUT fp32 (reference returns float32 -> d_out is float*).
// Correctness-first fp32 VALU pipeline (round-4 structure), out dtype fixed.
typedef __attribute__((ext_vector_type(4))) float f32x4;

// ---------------------------------------------------------------------------
// K1: assn[65536][80] = x[65536][512] @ clusters[512][80], fp32 VALU.
//     + per-block (32-row) column sum/sumsq partials for BN stats.
// grid 2048 x 256. thread (r=t>>3, cg=t&7): 1 row x 10 cols.
// ---------------------------------------------------------------------------
__global__ __launch_bounds__(256) void k1_gemm1(
    const float* __restrict__ x, const float* __restrict__ clus,
    float* __restrict__ raw, float* __restrict__ part) {
  __shared__ float lc[128 * 80];      // 40,960 B
  __shared__ float lx[32 * 130];      // 16,640 B
  const int t = threadIdx.x;
  const int r = t >> 3, cg = t & 7;
  const int rbase = blockIdx.x * 32;
  float acc[10];
#pragma unroll
  for (int j = 0; j < 10; ++j) acc[j] = 0.f;

  for (int k0 = 0; k0 < 512; k0 += 128) {
    __syncthreads();                   // previous chunk fully consumed
    const float4* src = (const float4*)(clus + (size_t)k0 * 80);
    for (int i = t; i < 2560; i += 256) ((float4*)lc)[i] = src[i];
    for (int i = t; i < 4096; i += 256) {
      int rr = i >> 7, kk = i & 127;
      lx[rr * 130 + kk] = x[(size_t)(rbase + rr) * 512 + k0 + kk];
    }
    __syncthreads();
    for (int kk = 0; kk < 128; ++kk) {
      float xv = lx[r * 130 + kk];
      const float* cp = &lc[kk * 80 + cg * 10];
      float2 c0 = *(const float2*)(cp + 0);
      float2 c1 = *(const float2*)(cp + 2);
      float2 c2v = *(const float2*)(cp + 4);
      float2 c3 = *(const float2*)(cp + 6);
      float2 c4 = *(const float2*)(cp + 8);
      acc[0] += xv * c0.x;  acc[1] += xv * c0.y;
      acc[2] += xv * c1.x;  acc[3] += xv * c1.y;
      acc[4] += xv * c2v.x; acc[5] += xv * c2v.y;
      acc[6] += xv * c3.x;  acc[7] += xv * c3.y;
      acc[8] += xv * c4.x;  acc[9] += xv * c4.y;
    }
  }
  __syncthreads();
#pragma unroll
  for (int j = 0; j < 10; ++j) {
    lx[r * 80 + cg * 10 + j] = acc[j];
    raw[(size_t)(rbase + r) * 80 + cg * 10 + j] = acc[j];
  }
  __syncthreads();
  if (t < 80) {
    float s = 0.f, q = 0.f;
    for (int rr = 0; rr < 32; ++rr) {
      float v = lx[rr * 80 + t];
      s += v; q += v * v;
    }
    part[(size_t)blockIdx.x * 320 + t] = s;
    part[(size_t)blockIdx.x * 320 + 160 + t] = q;
  }
}

// ---------------------------------------------------------------------------
// K2: finalize BN stats -> scale[80] | shift[80]. grid 80 x 64.
// ---------------------------------------------------------------------------
__global__ __launch_bounds__(64) void k2_stats(
    const float* __restrict__ part, const float* __restrict__ gamma,
    const float* __restrict__ beta, float* __restrict__ scsh) {
  int c = blockIdx.x, t = threadIdx.x;
  float s1 = 0.f, s2 = 0.f;
  for (int p = t; p < 2048; p += 64) {
    s1 += part[(size_t)p * 320 + c];
    s2 += part[(size_t)p * 320 + 160 + c];
  }
#pragma unroll
  for (int o = 1; o < 64; o <<= 1) { s1 += __shfl_xor(s1, o); s2 += __shfl_xor(s2, o); }
  if (t == 0) {
    float mean = s1 * (1.f / 65536.f);
    float var = s2 * (1.f / 65536.f) - mean * mean;
    float sc = rsqrtf(var + 1e-5f) * gamma[c];
    scsh[c] = sc;
    scsh[80 + c] = beta[c] - mean * sc;
  }
}

// ---------------------------------------------------------------------------
// K3: BN + softmax(80); write p fp32 IN PLACE into raw[:, 0:64].
// grid 1024 x 256; 4 lanes per row x 20 cols; shfl_xor(1)/(2) row reduce.
// ---------------------------------------------------------------------------
__global__ __launch_bounds__(256) void k3_bnsoft(
    float* __restrict__ raw, const float* __restrict__ scsh) {
  __shared__ float sc[80], sh[80];
  const int t = threadIdx.x;
  if (t < 80) sc[t] = scsh[t];
  else if (t < 160) sh[t - 80] = scsh[t];
  __syncthreads();

  const int r = t >> 2, cg = t & 3;
  float* rp = raw + ((size_t)blockIdx.x * 64 + r) * 80;
  const int cbase = cg * 20;

  float y[20];
#pragma unroll
  for (int j = 0; j < 20; j += 4) {
    float4 v = *(const float4*)(rp + cbase + j);
    y[j] = v.x; y[j + 1] = v.y; y[j + 2] = v.z; y[j + 3] = v.w;
  }
  float mx = -3.0e38f;
#pragma unroll
  for (int j = 0; j < 20; ++j) {
    int c = cbase + j;
    y[j] = y[j] * sc[c] + sh[c];
    mx = fmaxf(mx, y[j]);
  }
  mx = fmaxf(mx, __shfl_xor(mx, 1));
  mx = fmaxf(mx, __shfl_xor(mx, 2));
  float sum = 0.f;
#pragma unroll
  for (int j = 0; j < 20; ++j) { y[j] = __expf(y[j] - mx); sum += y[j]; }
  sum += __shfl_xor(sum, 1);
  sum += __shfl_xor(sum, 2);
  float inv = 1.0f / sum;
#pragma unroll
  for (int j = 0; j < 20; ++j) {
    int c = cbase + j;
    if (c < 64) rp[c] = y[j] * inv;
  }
}

// ---------------------------------------------------------------------------
// K4: vlad[b][d][k] = sum_n x[b][n][d]*p[b][n][k] - (sum_n p[b][n][k])*c2[d][k]
// grid 512 (32 b x 16 d-tiles of 32) x 256. fp32 VALU outer product.
// ---------------------------------------------------------------------------
__global__ __launch_bounds__(256) void k4_gemm2(
    const float* __restrict__ x, const float* __restrict__ assn,
    const float* __restrict__ c2, float* __restrict__ vlad) {
  __shared__ float lx[32 * 34];       // [n][34] padded
  __shared__ float lp[32 * 68];       // [n][68] padded
  const int t = threadIdx.x;
  const int b = blockIdx.x >> 4, dt = blockIdx.x & 15, d0 = dt * 32;
  const int tk = t & 15, td = t >> 4;

  f32x4 a0 = 0.f, a1 = 0.f, ps = 0.f;
  const float* xb = x + (size_t)b * 2048 * 512 + d0;
  const float* pb = assn + (size_t)b * 2048 * 80;

  for (int n0 = 0; n0 < 2048; n0 += 32) {
#pragma unroll
    for (int i = 0; i < 4; ++i) {
      int idx = t + i * 256; int n = idx >> 5, d = idx & 31;
      lx[n * 34 + d] = xb[(size_t)(n0 + n) * 512 + d];
    }
#pragma unroll
    for (int i = 0; i < 8; ++i) {
      int idx = t + i * 256; int n = idx >> 6, k = idx & 63;
      lp[n * 68 + k] = pb[(size_t)(n0 + n) * 80 + k];
    }
    __syncthreads();
#pragma unroll
    for (int nn = 0; nn < 32; ++nn) {
      float2 xv = *(const float2*)&lx[nn * 34 + td * 2];
      f32x4 pv = *(const f32x4*)&lp[nn * 68 + tk * 4];
      a0 += xv.x * pv;
      a1 += xv.y * pv;
      ps += pv;
    }
    __syncthreads();
  }

  const int k4 = tk * 4;
#pragma unroll
  for (int dd = 0; dd < 2; ++dd) {
    int d = d0 + td * 2 + dd;
    f32x4 rr = dd ? a1 : a0;
    float4 o;
    o.x = rr[0] - ps[0] * c2[d * 64 + k4 + 0];
    o.y = rr[1] - ps[1] * c2[d * 64 + k4 + 1];
    o.z = rr[2] - ps[2] * c2[d * 64 + k4 + 2];
    o.w = rr[3] - ps[3] * c2[d * 64 + k4 + 3];
    *(float4*)&vlad[((size_t)b * 512 + d) * 64 + k4] = o;
  }
}

// ---------------------------------------------------------------------------
// K5: intra-norm over D per (b,k), global L2 per b, FP32 out. grid 32 x 1024.
// ---------------------------------------------------------------------------
__global__ __launch_bounds__(1024) void k5_norm(
    const float* __restrict__ vlad, float* __restrict__ out) {
  __shared__ float partl[16 * 64];
  __shared__ float linv[64];
  __shared__ float gsc;
  const int t = threadIdx.x, b = blockIdx.x;
  const float* vb = vlad + (size_t)b * 32768;
  const int k = t & 63, dg = t >> 6;
  float s = 0.f;
#pragma unroll 8
  for (int j = 0; j < 32; ++j) {
    float v = vb[(dg * 32 + j) * 64 + k];
    s += v * v;
  }
  partl[dg * 64 + k] = s;
  __syncthreads();
  if (t < 64) {
    float ssq = 0.f;
#pragma unroll
    for (int g = 0; g < 16; ++g) ssq += partl[g * 64 + t];
    float iv = 1.0f / fmaxf(sqrtf(ssq), 1e-12f);
    linv[t] = iv;
    float contrib = ssq * iv * iv;
#pragma unroll
    for (int o = 1; o < 64; o <<= 1) contrib += __shfl_xor(contrib, o);
    if (t == 0) gsc = 1.0f / fmaxf(sqrtf(contrib), 1e-12f);
  }
  __syncthreads();
  const float gg = gsc;
  for (int i = t; i < 32768; i += 1024) {
    out[(size_t)b * 32768 + i] = vb[i] * linv[i & 63] * gg;
  }
}

// ---------------------------------------------------------------------------
// Workspace layout (bytes), total 27,787,904:
//   raw    @ 0         : 65536*80*4   = 20,971,520   (cols 0:64 become p in K3)
//   part   @ 20971520  : 2048*320*4   =  2,621,440
//   scsh   @ 23592960  : 160*4        =        640
//   vlad   @ 23593600  : 32*512*64*4  =  4,194,304
// ---------------------------------------------------------------------------
extern "C" void kernel_launch(void* const* d_in, const int* in_sizes, int n_in,
                              void* d_out, int out_size, void* d_ws, size_t ws_size,
                              hipStream_t stream) {
  const float* x         = (const float*)d_in[0];
  const float* clusters  = (const float*)d_in[1];
  const float* clusters2 = (const float*)d_in[2];
  const float* gamma     = (const float*)d_in[3];
  const float* beta      = (const float*)d_in[4];
  float* out = (float*)d_out;          // reference output dtype = float32
  char* ws = (char*)d_ws;

  float* raw  = (float*)(ws + 0);
  float* part = (float*)(ws + 20971520);
  float* scsh = (float*)(ws + 23592960);
  float* vlad = (float*)(ws + 23593600);

  hipLaunchKernelGGL(k1_gemm1,  dim3(2048), dim3(256),  0, stream, x, clusters, raw, part);
  hipLaunchKernelGGL(k2_stats,  dim3(80),   dim3(64),   0, stream, part, gamma, beta, scsh);
  hipLaunchKernelGGL(k3_bnsoft, dim3(1024), dim3(256),  0, stream, raw, scsh);
  hipLaunchKernelGGL(k4_gemm2,  dim3(512),  dim3(256),  0, stream, x, raw, clusters2, vlad);
  hipLaunchKernelGGL(k5_norm,   dim3(32),   dim3(1024), 0, stream, vlad, out);
}

// Round 6
// 312.494 us; speedup vs baseline: 2.3100x; 2.3100x over previous
//
#include <hip/hip_runtime.h>
#include <hip/hip_bf16.h>
#include <stdint.h>

// Problem: B=32, N=2048, D=512, K=64, G=16, M=B*N=65536, C=K+G=80
// Inputs fp32; OUTPUT fp32.
typedef __attribute__((ext_vector_type(8))) short short8;
typedef __attribute__((ext_vector_type(4))) float f32x4;

__device__ __forceinline__ uint16_t f2b(float f) {   // RNE fp32->bf16
  uint32_t u = __float_as_uint(f);
  return (uint16_t)((u + 0x7FFFu + ((u >> 16) & 1u)) >> 16);
}
// pack two fp32 bit-patterns -> bf16x2 (round-half-up) via v_perm
__device__ __forceinline__ uint32_t pk2(uint32_t lo, uint32_t hi) {
  return __builtin_amdgcn_perm(hi + 0x8000u, lo + 0x8000u, 0x07060302u);
}

// ---------------------------------------------------------------------------
// K0: emit clusters (fp32 [512][80]) as bf16 in MFMA B-fragment order:
// cB[(kk*320 + n*64 + lr*4 + q)*8 + i] = clusters[kk*32 + q*8 + i][n*16 + lr]
// ---------------------------------------------------------------------------
__global__ void k0_prep(const float* __restrict__ clusters,
                        uint16_t* __restrict__ cB) {
  int gid = blockIdx.x * 256 + threadIdx.x;
  if (gid < 40960) {
    int chunk = gid >> 3, i = gid & 7;
    int kk = chunk / 320, rem = chunk - kk * 320;
    int n = rem >> 6, rem2 = rem & 63;
    int lr = rem2 >> 2, q = rem2 & 3;
    cB[gid] = f2b(clusters[(kk * 32 + q * 8 + i) * 80 + n * 16 + lr]);
  }
}

// ---------------------------------------------------------------------------
// K1: raw[65536][80] = bf16(x) @ bf16(clusters)  (MFMA 16x16x32)
//     + per-block column sum/sumsq partials for BN stats.
// grid 1024 x 256; block = 64 rows; wave = 16 rows (m=1), 5 col-frags.
// LDS: 40KB half of fragment-ordered B at a time (2 phases) -> 4 blocks/CU.
// ---------------------------------------------------------------------------
__global__ __launch_bounds__(256) void k1_gemm1(
    const float* __restrict__ x, const uint16_t* __restrict__ cB,
    float* __restrict__ raw, float* __restrict__ part) {
  __shared__ uint16_t lB[80 * 256];       // 40,960 B
  const int t = threadIdx.x;
  const int w = t >> 6, lane = t & 63, q = lane >> 4, lr = lane & 15;
  const int rowbase = blockIdx.x * 64 + w * 16;

  f32x4 acc[5];
#pragma unroll
  for (int n = 0; n < 5; ++n) acc[n] = 0.f;

  const float* xa = x + (size_t)(rowbase + lr) * 512 + q * 8;

  for (int h = 0; h < 2; ++h) {
    if (h) __syncthreads();
#pragma unroll 2
    for (int idx = t; idx < 2560; idx += 256)
      *(uint4*)&lB[idx * 8] = ((const uint4*)cB)[h * 2560 + idx];
    __syncthreads();
#pragma unroll
    for (int kk8 = 0; kk8 < 8; ++kk8) {
      const int kk = h * 8 + kk8;
      uint4 u0 = *(const uint4*)(xa + kk * 32);
      uint4 u1 = *(const uint4*)(xa + kk * 32 + 4);
      union { short8 s; uint32_t u[4]; } av;
      av.u[0] = pk2(u0.x, u0.y); av.u[1] = pk2(u0.z, u0.w);
      av.u[2] = pk2(u1.x, u1.y); av.u[3] = pk2(u1.z, u1.w);
#pragma unroll
      for (int n = 0; n < 5; ++n) {
        short8 bf = *(const short8*)&lB[(size_t)((kk8 * 5 + n) * 64 + lr * 4 + q) * 8];
        acc[n] = __builtin_amdgcn_mfma_f32_16x16x32_bf16(av.s, bf, acc[n], 0, 0, 0);
      }
    }
  }
  __syncthreads();                       // done with lB; reuse as float scratch

  // epilogue: C/D layout col=lane&15, row=q*4+r. Store + column stats.
  float sums[5], sqs[5];
#pragma unroll
  for (int n = 0; n < 5; ++n) {
    float s = 0.f, qq = 0.f;
#pragma unroll
    for (int r = 0; r < 4; ++r) {
      float v = acc[n][r];
      s += v; qq += v * v;
      raw[(size_t)(rowbase + q * 4 + r) * 80 + n * 16 + lr] = v;
    }
    s += __shfl_xor(s, 16);  s += __shfl_xor(s, 32);   // sum over q -> 16 rows
    qq += __shfl_xor(qq, 16); qq += __shfl_xor(qq, 32);
    sums[n] = s; sqs[n] = qq;
  }

  float* sf = (float*)lB;                // [4][160] sums then [4][160] sumsqs
  if (lane < 16) {
#pragma unroll
    for (int n = 0; n < 5; ++n) {
      sf[w * 160 + n * 16 + lr] = sums[n];
      sf[640 + w * 160 + n * 16 + lr] = sqs[n];
    }
  }
  __syncthreads();
  if (t < 160) {
    float a0 = sf[t] + sf[160 + t] + sf[320 + t] + sf[480 + t];
    float b0 = sf[640 + t] + sf[800 + t] + sf[960 + t] + sf[1120 + t];
    part[(size_t)blockIdx.x * 320 + t] = a0;
    part[(size_t)blockIdx.x * 320 + 160 + t] = b0;
  }
}

// ---------------------------------------------------------------------------
// K2: finalize BN stats -> scale[80] | shift[80]; zero a_sum. grid 80 x 64.
// ---------------------------------------------------------------------------
__global__ __launch_bounds__(64) void k2_stats(
    const float* __restrict__ part, const float* __restrict__ gamma,
    const float* __restrict__ beta, float* __restrict__ scsh,
    float* __restrict__ a_sum) {
  int c = blockIdx.x, t = threadIdx.x;
  int gid = c * 64 + t;
  if (gid < 2048) a_sum[gid] = 0.f;
  float s1 = 0.f, s2 = 0.f;
  for (int p = t; p < 1024; p += 64) {
    s1 += part[(size_t)p * 320 + c];
    s2 += part[(size_t)p * 320 + 160 + c];
  }
#pragma unroll
  for (int o = 1; o < 64; o <<= 1) { s1 += __shfl_xor(s1, o); s2 += __shfl_xor(s2, o); }
  if (t == 0) {
    float mean = s1 * (1.f / 65536.f);
    float var = s2 * (1.f / 65536.f) - mean * mean;
    float sc = rsqrtf(var + 1e-5f) * gamma[c];
    scsh[c] = sc;
    scsh[80 + c] = beta[c] - mean * sc;
  }
}

// ---------------------------------------------------------------------------
// K3: BN + softmax(80); p fp32 in place into raw[:, 0:64]; a_sum[b][k] += col
// sums (LDS reduce + 64 atomics/block). grid 1024 x 256; 4 lanes/row.
// ---------------------------------------------------------------------------
__global__ __launch_bounds__(256) void k3_bnsoft(
    float* __restrict__ raw, const float* __restrict__ scsh,
    float* __restrict__ a_sum) {
  __shared__ float sc[80], sh[80];
  __shared__ float lpd[64 * 68];
  const int t = threadIdx.x;
  if (t < 80) sc[t] = scsh[t];
  else if (t < 160) sh[t - 80] = scsh[t];
  __syncthreads();

  const int r = t >> 2, cg = t & 3;
  float* rp = raw + ((size_t)blockIdx.x * 64 + r) * 80;
  const int cbase = cg * 20;

  float y[20];
#pragma unroll
  for (int j = 0; j < 20; j += 4) {
    float4 v = *(const float4*)(rp + cbase + j);
    y[j] = v.x; y[j + 1] = v.y; y[j + 2] = v.z; y[j + 3] = v.w;
  }
  float mx = -3.0e38f;
#pragma unroll
  for (int j = 0; j < 20; ++j) {
    int c = cbase + j;
    y[j] = y[j] * sc[c] + sh[c];
    mx = fmaxf(mx, y[j]);
  }
  mx = fmaxf(mx, __shfl_xor(mx, 1));
  mx = fmaxf(mx, __shfl_xor(mx, 2));
  float sum = 0.f;
#pragma unroll
  for (int j = 0; j < 20; ++j) { y[j] = __expf(y[j] - mx); sum += y[j]; }
  sum += __shfl_xor(sum, 1);
  sum += __shfl_xor(sum, 2);
  float inv = 1.0f / sum;
#pragma unroll
  for (int j = 0; j < 20; ++j) {
    int c = cbase + j;
    if (c < 64) {
      float p = y[j] * inv;
      rp[c] = p;
      lpd[r * 68 + c] = p;
    }
  }
  __syncthreads();
  if (t < 64) {
    float s = 0.f;
#pragma unroll 8
    for (int rr = 0; rr < 64; ++rr) s += lpd[rr * 68 + t];
    atomicAdd(&a_sum[(blockIdx.x >> 5) * 64 + t], s);
  }
}

// ---------------------------------------------------------------------------
// K4: vpart[nb][b][d][k] = sum_{n in half nb} x[b][n][d]*p[b][n][k]
// grid 1024 (2 nb x 32 b x 16 dt) x 256; software-pipelined (reg prefetch).
// ---------------------------------------------------------------------------
__global__ __launch_bounds__(256) void k4_gemm2(
    const float* __restrict__ x, const float* __restrict__ assn,
    float* __restrict__ vpart) {
  __shared__ float lx[32 * 36];       // [n][36]
  __shared__ float lp[32 * 68];       // [n][68]
  const int t = threadIdx.x;
  const int nb = blockIdx.x >> 9;
  const int b = (blockIdx.x >> 4) & 31;
  const int d0 = (blockIdx.x & 15) * 32;
  const int tk = t & 15, td = t >> 4;

  f32x4 a0 = 0.f, a1 = 0.f;
  const float* xb = x + ((size_t)b * 2048 + (size_t)nb * 1024) * 512 + d0;
  const float* pb = assn + ((size_t)b * 2048 + (size_t)nb * 1024) * 80;

  const int xn = t >> 3, xdq = t & 7;   // lx float4: n = t>>3, d = xdq*4
  const int pn = t >> 4, pk = t & 15;   // lp float4: rows pn and pn+16
  float4 rx, rp0, rp1;
  rx  = *(const float4*)(xb + (size_t)xn * 512 + xdq * 4);
  rp0 = *(const float4*)(pb + (size_t)pn * 80 + pk * 4);
  rp1 = *(const float4*)(pb + (size_t)(pn + 16) * 80 + pk * 4);

  for (int c = 0; c < 32; ++c) {
    __syncthreads();
    *(float4*)&lx[xn * 36 + xdq * 4] = rx;
    *(float4*)&lp[pn * 68 + pk * 4] = rp0;
    *(float4*)&lp[(pn + 16) * 68 + pk * 4] = rp1;
    __syncthreads();
    if (c < 31) {                        // prefetch next chunk during compute
      const float* xc = xb + (size_t)(c + 1) * 32 * 512;
      const float* pc = pb + (size_t)(c + 1) * 32 * 80;
      rx  = *(const float4*)(xc + (size_t)xn * 512 + xdq * 4);
      rp0 = *(const float4*)(pc + (size_t)pn * 80 + pk * 4);
      rp1 = *(const float4*)(pc + (size_t)(pn + 16) * 80 + pk * 4);
    }
#pragma unroll
    for (int nn = 0; nn < 32; ++nn) {
      float2 xv = *(const float2*)&lx[nn * 36 + td * 2];
      f32x4 pv = *(const f32x4*)&lp[nn * 68 + tk * 4];
      a0 += xv.x * pv;
      a1 += xv.y * pv;
    }
  }

  const int k4 = tk * 4;
  float* vp = vpart + (size_t)nb * 1048576 + (size_t)b * 32768;
#pragma unroll
  for (int dd = 0; dd < 2; ++dd) {
    int d = d0 + td * 2 + dd;
    f32x4 rr = dd ? a1 : a0;
    float4 o; o.x = rr[0]; o.y = rr[1]; o.z = rr[2]; o.w = rr[3];
    *(float4*)&vp[(size_t)d * 64 + k4] = o;
  }
}

// ---------------------------------------------------------------------------
// K5: v = vp0 + vp1 - a_sum[k]*c2[d][k]; intra-norm over D; global L2; fp32.
// grid 32 x 1024.
// ---------------------------------------------------------------------------
__global__ __launch_bounds__(1024) void k5_norm(
    const float* __restrict__ vpart, const float* __restrict__ a_sum,
    const float* __restrict__ c2, float* __restrict__ out) {
  __shared__ float partl[16 * 64];
  __shared__ float linv[64];
  __shared__ float gsc;
  __shared__ float las[64];
  const int t = threadIdx.x, b = blockIdx.x;
  if (t < 64) las[t] = a_sum[b * 64 + t];
  __syncthreads();
  const float* v0 = vpart + (size_t)b * 32768;
  const float* v1 = v0 + 1048576;
  const int k = t & 63, dg = t >> 6;
  const float as = las[k];
  float s = 0.f;
#pragma unroll 8
  for (int j = 0; j < 32; ++j) {
    int i = (dg * 32 + j) * 64 + k;
    float v = v0[i] + v1[i] - as * c2[i];
    s += v * v;
  }
  partl[dg * 64 + k] = s;
  __syncthreads();
  if (t < 64) {
    float ssq = 0.f;
#pragma unroll
    for (int g = 0; g < 16; ++g) ssq += partl[g * 64 + t];
    float iv = 1.0f / fmaxf(sqrtf(ssq), 1e-12f);
    linv[t] = iv;
    float contrib = ssq * iv * iv;
#pragma unroll
    for (int o = 1; o < 64; o <<= 1) contrib += __shfl_xor(contrib, o);
    if (t == 0) gsc = 1.0f / fmaxf(sqrtf(contrib), 1e-12f);
  }
  __syncthreads();
  const float gg = gsc;
  for (int i = t; i < 32768; i += 1024) {
    float v = v0[i] + v1[i] - las[i & 63] * c2[i];
    out[(size_t)b * 32768 + i] = v * linv[i & 63] * gg;
  }
}

// ---------------------------------------------------------------------------
// Workspace (bytes), total 30,761,600:
//   cB     @ 0        : 40960*2       =    81,920
//   part   @ 81920    : 1024*320*4    = 1,310,720
//   scsh   @ 1392640  : 160*4         =       640
//   a_sum  @ 1393280  : 2048*4        =     8,192
//   raw    @ 1401472  : 65536*80*4    = 20,971,520   (cols 0:64 -> p after K3)
//   vpart  @ 22372992 : 2*32*512*64*4 =  8,388,608
// ---------------------------------------------------------------------------
extern "C" void kernel_launch(void* const* d_in, const int* in_sizes, int n_in,
                              void* d_out, int out_size, void* d_ws, size_t ws_size,
                              hipStream_t stream) {
  const float* x         = (const float*)d_in[0];
  const float* clusters  = (const float*)d_in[1];
  const float* clusters2 = (const float*)d_in[2];
  const float* gamma     = (const float*)d_in[3];
  const float* beta      = (const float*)d_in[4];
  float* out = (float*)d_out;
  char* ws = (char*)d_ws;

  uint16_t* cB = (uint16_t*)(ws + 0);
  float* part  = (float*)(ws + 81920);
  float* scsh  = (float*)(ws + 1392640);
  float* a_sum = (float*)(ws + 1393280);
  float* raw   = (float*)(ws + 1401472);
  float* vpart = (float*)(ws + 22372992);

  hipLaunchKernelGGL(k0_prep,   dim3(160),  dim3(256),  0, stream, clusters, cB);
  hipLaunchKernelGGL(k1_gemm1,  dim3(1024), dim3(256),  0, stream, x, cB, raw, part);
  hipLaunchKernelGGL(k2_stats,  dim3(80),   dim3(64),   0, stream, part, gamma, beta, scsh, a_sum);
  hipLaunchKernelGGL(k3_bnsoft, dim3(1024), dim3(256),  0, stream, raw, scsh, a_sum);
  hipLaunchKernelGGL(k4_gemm2,  dim3(1024), dim3(256),  0, stream, x, raw, vpart);
  hipLaunchKernelGGL(k5_norm,   dim3(32),   dim3(1024), 0, stream, vpart, a_sum, clusters2, out);
}

// Round 7
// 258.289 us; speedup vs baseline: 2.7948x; 1.2099x over previous
//
#include <hip/hip_runtime.h>
#include <hip/hip_bf16.h>
#include <stdint.h>

// Problem: B=32, N=2048, D=512, K=64, G=16, M=B*N=65536, C=K+G=80
// Inputs fp32; OUTPUT fp32.
typedef __attribute__((ext_vector_type(8))) short short8;
typedef __attribute__((ext_vector_type(4))) float f32x4;

__device__ __forceinline__ float b2f(uint16_t u) {
  union { uint32_t i; float f; } v; v.i = ((uint32_t)u) << 16; return v.f;
}
__device__ __forceinline__ uint16_t f2b(float f) {   // RNE fp32->bf16
  uint32_t u = __float_as_uint(f);
  return (uint16_t)((u + 0x7FFFu + ((u >> 16) & 1u)) >> 16);
}
// pack two fp32 bit-patterns -> bf16x2 (lo in low half) via v_perm
__device__ __forceinline__ uint32_t pk2(uint32_t lo, uint32_t hi) {
  return __builtin_amdgcn_perm(hi + 0x8000u, lo + 0x8000u, 0x07060302u);
}

// ---------------------------------------------------------------------------
// K0: clusters fp32 [512][80] -> bf16 MFMA B-fragments, [chunk][q][lr] order
// (lr stride 16B -> 2-way LDS conflicts = free on the K1 b128 reads):
// cB[(((kk*5+n)*4+q)*16+lr)*8+i] = clusters[kk*32+q*8+i][n*16+lr]
// ---------------------------------------------------------------------------
__global__ void k0_prep(const float* __restrict__ clusters,
                        uint16_t* __restrict__ cB) {
  int gid = blockIdx.x * 256 + threadIdx.x;
  if (gid < 40960) {
    int i = gid & 7, chunk = gid >> 3;
    int lr = chunk & 15, q = (chunk >> 4) & 3, c5 = chunk >> 6;
    int n = c5 % 5, kk = c5 / 5;
    cB[gid] = f2b(clusters[(kk * 32 + q * 8 + i) * 80 + n * 16 + lr]);
  }
}

// ---------------------------------------------------------------------------
// K1: raw[65536][80] = bf16(x) @ bf16(clusters)  (MFMA 16x16x32)
//     + per-block column sum/sumsq partials. grid 512 x 256; 128 rows/block,
//     32 rows/wave (m=2). B staged in two 40KB halves.
// ---------------------------------------------------------------------------
__global__ __launch_bounds__(256) void k1_gemm1(
    const float* __restrict__ x, const uint16_t* __restrict__ cB,
    float* __restrict__ raw, float* __restrict__ part) {
  __shared__ __align__(16) uint16_t lB[80 * 256];   // 40,960 B
  const int t = threadIdx.x;
  const int w = t >> 6, lane = t & 63, q = lane >> 4, lr = lane & 15;
  const int rbase = blockIdx.x * 128 + w * 32;

  f32x4 acc[2][5];
#pragma unroll
  for (int m = 0; m < 2; ++m)
#pragma unroll
    for (int n = 0; n < 5; ++n) acc[m][n] = 0.f;

  const float* xa = x + (size_t)(rbase + lr) * 512 + q * 8;

  for (int h = 0; h < 2; ++h) {
    if (h) __syncthreads();
#pragma unroll 2
    for (int idx = t; idx < 2560; idx += 256)
      *(uint4*)&lB[idx * 8] = ((const uint4*)cB)[h * 2560 + idx];
    __syncthreads();
#pragma unroll
    for (int kk8 = 0; kk8 < 8; ++kk8) {
      const int kk = h * 8 + kk8;
      short8 a[2], bf[5];
#pragma unroll
      for (int m = 0; m < 2; ++m) {
        uint4 u0 = *(const uint4*)(xa + (size_t)m * 16 * 512 + kk * 32);
        uint4 u1 = *(const uint4*)(xa + (size_t)m * 16 * 512 + kk * 32 + 4);
        union { short8 s; uint32_t u[4]; } av;
        av.u[0] = pk2(u0.x, u0.y); av.u[1] = pk2(u0.z, u0.w);
        av.u[2] = pk2(u1.x, u1.y); av.u[3] = pk2(u1.z, u1.w);
        a[m] = av.s;
      }
#pragma unroll
      for (int n = 0; n < 5; ++n)
        bf[n] = *(const short8*)&lB[(((kk8 * 5 + n) * 4 + q) * 16 + lr) * 8];
#pragma unroll
      for (int m = 0; m < 2; ++m)
#pragma unroll
        for (int n = 0; n < 5; ++n)
          acc[m][n] = __builtin_amdgcn_mfma_f32_16x16x32_bf16(a[m], bf[n], acc[m][n], 0, 0, 0);
    }
  }
  __syncthreads();

  float sums[5], sqs[5];
#pragma unroll
  for (int n = 0; n < 5; ++n) {
    float s = 0.f, qq = 0.f;
#pragma unroll
    for (int m = 0; m < 2; ++m) {
#pragma unroll
      for (int r = 0; r < 4; ++r) {
        float v = acc[m][n][r];
        s += v; qq += v * v;
        raw[(size_t)(rbase + m * 16 + q * 4 + r) * 80 + n * 16 + lr] = v;
      }
    }
    s += __shfl_xor(s, 16);  s += __shfl_xor(s, 32);
    qq += __shfl_xor(qq, 16); qq += __shfl_xor(qq, 32);
    sums[n] = s; sqs[n] = qq;
  }

  float* sf = (float*)lB;
  if (lane < 16) {
#pragma unroll
    for (int n = 0; n < 5; ++n) {
      sf[w * 160 + n * 16 + lr] = sums[n];
      sf[640 + w * 160 + n * 16 + lr] = sqs[n];
    }
  }
  __syncthreads();
  if (t < 160) {
    float a0 = sf[t] + sf[160 + t] + sf[320 + t] + sf[480 + t];
    float b0 = sf[640 + t] + sf[800 + t] + sf[960 + t] + sf[1120 + t];
    part[(size_t)blockIdx.x * 320 + t] = a0;
    part[(size_t)blockIdx.x * 320 + 160 + t] = b0;
  }
}

// ---------------------------------------------------------------------------
// K2: BN stats -> scale[80] | shift[80]; zero a_sum. grid 80 x 64.
// ---------------------------------------------------------------------------
__global__ __launch_bounds__(64) void k2_stats(
    const float* __restrict__ part, const float* __restrict__ gamma,
    const float* __restrict__ beta, float* __restrict__ scsh,
    float* __restrict__ a_sum) {
  int c = blockIdx.x, t = threadIdx.x;
  int gid = c * 64 + t;
  if (gid < 2048) a_sum[gid] = 0.f;
  float s1 = 0.f, s2 = 0.f;
  for (int p = t; p < 512; p += 64) {
    s1 += part[(size_t)p * 320 + c];
    s2 += part[(size_t)p * 320 + 160 + c];
  }
#pragma unroll
  for (int o = 1; o < 64; o <<= 1) { s1 += __shfl_xor(s1, o); s2 += __shfl_xor(s2, o); }
  if (t == 0) {
    float mean = s1 * (1.f / 65536.f);
    float var = s2 * (1.f / 65536.f) - mean * mean;
    float sc = rsqrtf(var + 1e-5f) * gamma[c];
    scsh[c] = sc;
    scsh[80 + c] = beta[c] - mean * sc;
  }
}

// ---------------------------------------------------------------------------
// K3: BN + softmax(80) -> p bf16 transposed pT[b][k][2048]; a_sum from the
// SAME bf16 p (consistency with K4). grid 1024 x 256; 64 rows/block.
// ---------------------------------------------------------------------------
__global__ __launch_bounds__(256) void k3_bnsoft(
    const float* __restrict__ raw, const float* __restrict__ scsh,
    uint16_t* __restrict__ pT, float* __restrict__ a_sum) {
  __shared__ float sc[80], sh[80];
  __shared__ __align__(16) uint16_t lpT[64 * 72];   // [k][n-local], stride 72
  __shared__ float apart[256];
  const int t = threadIdx.x;
  if (t < 80) sc[t] = scsh[t];
  else if (t < 160) sh[t - 80] = scsh[t];
  __syncthreads();

  const int r = t >> 2, cg = t & 3;
  const float* rp = raw + ((size_t)blockIdx.x * 64 + r) * 80;
  const int cbase = cg * 20;

  float y[20];
#pragma unroll
  for (int j = 0; j < 20; j += 4) {
    float4 v = *(const float4*)(rp + cbase + j);
    y[j] = v.x; y[j + 1] = v.y; y[j + 2] = v.z; y[j + 3] = v.w;
  }
  float mx = -3.0e38f;
#pragma unroll
  for (int j = 0; j < 20; ++j) {
    int c = cbase + j;
    y[j] = y[j] * sc[c] + sh[c];
    mx = fmaxf(mx, y[j]);
  }
  mx = fmaxf(mx, __shfl_xor(mx, 1));
  mx = fmaxf(mx, __shfl_xor(mx, 2));
  float sum = 0.f;
#pragma unroll
  for (int j = 0; j < 20; ++j) { y[j] = __expf(y[j] - mx); sum += y[j]; }
  sum += __shfl_xor(sum, 1);
  sum += __shfl_xor(sum, 2);
  float inv = 1.0f / sum;
#pragma unroll
  for (int j = 0; j < 20; ++j) {
    int c = cbase + j;
    if (c < 64) lpT[c * 72 + r] = f2b(y[j] * inv);   // transposed in LDS
  }
  __syncthreads();

  // writer: thread (k=t>>2, ng=t&3) handles n-local ng*16..+15 of row k
  {
    int k = t >> 2, ng = t & 3;
    uint4 v0 = *(const uint4*)&lpT[k * 72 + ng * 16];
    uint4 v1 = *(const uint4*)&lpT[k * 72 + ng * 16 + 8];
    int b = blockIdx.x >> 5;
    int n0 = (blockIdx.x & 31) * 64;
    uint16_t* dst = pT + ((size_t)b * 64 + k) * 2048 + n0 + ng * 16;
    *(uint4*)dst = v0;
    *((uint4*)dst + 1) = v1;
    // a_sum partial from the same bf16 values
    const uint16_t* pv = &lpT[k * 72 + ng * 16];
    float s = 0.f;
#pragma unroll
    for (int i = 0; i < 16; ++i) s += b2f(pv[i]);
    apart[k * 4 + ng] = s;
  }
  __syncthreads();
  if (t < 64) {
    float s = apart[t * 4] + apart[t * 4 + 1] + apart[t * 4 + 2] + apart[t * 4 + 3];
    atomicAdd(&a_sum[(blockIdx.x >> 5) * 64 + t], s);
  }
}

// ---------------------------------------------------------------------------
// K4: vpart[nb][b][d][k] = sum_{n in half} x[b][n][d]*p[b][n][k]  (MFMA bf16)
// grid 512 (2 nb x 32 b x 8 dt of 64 d) x 256. x transposed to bf16 through
// LDS (swizzled [d][n] rows); pT read bf16. Double-buffered, 2-deep prefetch.
// ---------------------------------------------------------------------------
__global__ __launch_bounds__(256) void k4_gemm2(
    const float* __restrict__ x, const uint16_t* __restrict__ pT,
    float* __restrict__ vpart) {
  __shared__ __align__(16) uint16_t sx[2][64 * 40];  // [d][n] stride 40
  __shared__ __align__(16) uint16_t sp[2][64 * 40];  // [k][n] stride 40
  const int t = threadIdx.x;
  const int nb = blockIdx.x >> 8;
  const int b = (blockIdx.x >> 3) & 31;
  const int d0 = (blockIdx.x & 7) * 64;
  const int w = t >> 6, lane = t & 63, q = lane >> 4, lr = lane & 15;
  const int dl = w * 16 + lr;                    // wave-local d row
  const int sw = ((dl >> 2) + (dl >> 4)) & 3;    // read swizzle

  const int dd = t & 63, g = t >> 6;             // x staging: d, n-group
  const int sg = ((dd >> 2) + (dd >> 4)) & 3;    // write swizzle
  const int pk_ = t >> 2, pnq = t & 3;           // p staging

  const float* xb = x + ((size_t)b * 2048 + (size_t)nb * 1024) * 512 + d0;
  const uint16_t* pb = pT + (size_t)b * 131072 + (size_t)nb * 1024;

  f32x4 acc[4];
#pragma unroll
  for (int j = 0; j < 4; ++j) acc[j] = 0.f;

  float xf[2][8];
  uint4 pf[2];

#define LOADC(c, si)                                                        \
  {                                                                         \
    const float* xc = xb + (size_t)(c) * 32 * 512;                          \
    _Pragma("unroll")                                                       \
    for (int jj = 0; jj < 8; ++jj)                                          \
      xf[si][jj] = xc[(size_t)(g * 8 + jj) * 512 + dd];                     \
    pf[si] = *(const uint4*)(pb + (size_t)pk_ * 2048 + (c) * 32 + pnq * 8); \
  }
#define STOREC(buf, si)                                                     \
  {                                                                         \
    uint16_t* xrow = &sx[buf][dd * 40 + (g ^ sg) * 8];                      \
    _Pragma("unroll")                                                       \
    for (int j = 0; j < 2; ++j) {                                           \
      *(uint32_t*)&xrow[j * 4] =                                            \
          pk2(__float_as_uint(xf[si][j * 4]), __float_as_uint(xf[si][j * 4 + 1])); \
      *(uint32_t*)&xrow[j * 4 + 2] =                                        \
          pk2(__float_as_uint(xf[si][j * 4 + 2]), __float_as_uint(xf[si][j * 4 + 3])); \
    }                                                                       \
    *(uint4*)&sp[buf][pk_ * 40 + pnq * 8] = pf[si];                         \
  }

  LOADC(0, 0)
  STOREC(0, 0)
  LOADC(1, 1)
  __syncthreads();

  for (int c = 0; c < 32; ++c) {
    const int cur = c & 1;
    if (c < 31) STOREC(cur ^ 1, (c + 1) & 1)
    if (c < 30) LOADC(c + 2, c & 1)
    const uint16_t* sxc = sx[cur];
    const uint16_t* spc = sp[cur];
    short8 af = *(const short8*)&sxc[dl * 40 + (q ^ sw) * 8];
#pragma unroll
    for (int j = 0; j < 4; ++j) {
      short8 bfj = *(const short8*)&spc[(j * 16 + lr) * 40 + q * 8];
      acc[j] = __builtin_amdgcn_mfma_f32_16x16x32_bf16(af, bfj, acc[j], 0, 0, 0);
    }
    __syncthreads();
  }
#undef LOADC
#undef STOREC

  float* vp = vpart + (size_t)nb * 1048576 + (size_t)b * 32768;
#pragma unroll
  for (int j = 0; j < 4; ++j)
#pragma unroll
    for (int r = 0; r < 4; ++r)
      vp[(size_t)(d0 + w * 16 + q * 4 + r) * 64 + j * 16 + lr] = acc[j][r];
}

// ---------------------------------------------------------------------------
// K5a: partial column sumsq of v = vp0+vp1-a_sum*c2. grid 512 (32b x 16dg).
// ---------------------------------------------------------------------------
__global__ __launch_bounds__(256) void k5a_ssq(
    const float* __restrict__ vpart, const float* __restrict__ a_sum,
    const float* __restrict__ c2, float* __restrict__ csq) {
  __shared__ float sred[256];
  const int t = threadIdx.x, b = blockIdx.x >> 4, dg = blockIdx.x & 15;
  const int k = t & 63, di = t >> 6;
  const float* v0 = vpart + (size_t)b * 32768;
  const float* v1 = v0 + 1048576;
  const float as = a_sum[b * 64 + k];
  float ssq = 0.f;
#pragma unroll
  for (int jj = 0; jj < 8; ++jj) {
    int i = (dg * 32 + di * 8 + jj) * 64 + k;
    float v = v0[i] + v1[i] - as * c2[i];
    ssq += v * v;
  }
  sred[di * 64 + k] = ssq;
  __syncthreads();
  if (t < 64) {
    csq[(size_t)blockIdx.x * 64 + t] =
        sred[t] + sred[64 + t] + sred[128 + t] + sred[192 + t];
  }
}

// ---------------------------------------------------------------------------
// K5b: linv[b][k], gscl[b]. grid 32 x 64.
// ---------------------------------------------------------------------------
__global__ __launch_bounds__(64) void k5b_fin(
    const float* __restrict__ csq, float* __restrict__ linv,
    float* __restrict__ gscl) {
  const int t = threadIdx.x, b = blockIdx.x;
  float ssq = 0.f;
#pragma unroll
  for (int dg = 0; dg < 16; ++dg) ssq += csq[(size_t)(b * 16 + dg) * 64 + t];
  float iv = 1.0f / fmaxf(sqrtf(ssq), 1e-12f);
  linv[b * 64 + t] = iv;
  float contrib = ssq * iv * iv;
#pragma unroll
  for (int o = 1; o < 64; o <<= 1) contrib += __shfl_xor(contrib, o);
  if (t == 0) gscl[b] = 1.0f / fmaxf(sqrtf(contrib), 1e-12f);
}

// ---------------------------------------------------------------------------
// K5c: out = v * linv[k] * gscl[b]. grid 512 (32b x 16seg) x 256.
// ---------------------------------------------------------------------------
__global__ __launch_bounds__(256) void k5c_norm(
    const float* __restrict__ vpart, const float* __restrict__ a_sum,
    const float* __restrict__ c2, const float* __restrict__ linv,
    const float* __restrict__ gscl, float* __restrict__ out) {
  __shared__ float lv[64], las[64];
  __shared__ float gs;
  const int t = threadIdx.x, b = blockIdx.x >> 4, seg = blockIdx.x & 15;
  if (t < 64) { lv[t] = linv[b * 64 + t]; las[t] = a_sum[b * 64 + t]; }
  if (t == 64) gs = gscl[b];
  __syncthreads();
  const float* v0 = vpart + (size_t)b * 32768;
  const float* v1 = v0 + 1048576;
  const float gg = gs;
#pragma unroll
  for (int u = 0; u < 2; ++u) {
    int i = seg * 2048 + u * 1024 + t * 4;
    int k0 = i & 63;
    float4 a = *(const float4*)(v0 + i);
    float4 bb = *(const float4*)(v1 + i);
    float4 cc = *(const float4*)(c2 + i);
    float4 o;
    o.x = (a.x + bb.x - las[k0 + 0] * cc.x) * lv[k0 + 0] * gg;
    o.y = (a.y + bb.y - las[k0 + 1] * cc.y) * lv[k0 + 1] * gg;
    o.z = (a.z + bb.z - las[k0 + 2] * cc.z) * lv[k0 + 2] * gg;
    o.w = (a.w + bb.w - las[k0 + 3] * cc.w) * lv[k0 + 3] * gg;
    *(float4*)&out[(size_t)b * 32768 + i] = o;
  }
}

// ---------------------------------------------------------------------------
// Workspace (bytes), total 38,634,240:
//   cB    @ 0        : 81,920
//   part  @ 81920    : 512*320*4    =   655,360
//   scsh  @ 737280   : 640
//   a_sum @ 737920   : 8,192
//   raw   @ 746112   : 65536*80*4   = 20,971,520
//   pT    @ 21717632 : 32*64*2048*2 =  8,388,608
//   vpart @ 30106240 : 2*32*32768*4 =  8,388,608
//   csq   @ 38494848 : 512*64*4     =   131,072
//   linv  @ 38625920 : 2048*4       =     8,192
//   gscl  @ 38634112 : 32*4         =       128
// ---------------------------------------------------------------------------
extern "C" void kernel_launch(void* const* d_in, const int* in_sizes, int n_in,
                              void* d_out, int out_size, void* d_ws, size_t ws_size,
                              hipStream_t stream) {
  const float* x         = (const float*)d_in[0];
  const float* clusters  = (const float*)d_in[1];
  const float* clusters2 = (const float*)d_in[2];
  const float* gamma     = (const float*)d_in[3];
  const float* beta      = (const float*)d_in[4];
  float* out = (float*)d_out;
  char* ws = (char*)d_ws;

  uint16_t* cB = (uint16_t*)(ws + 0);
  float* part  = (float*)(ws + 81920);
  float* scsh  = (float*)(ws + 737280);
  float* a_sum = (float*)(ws + 737920);
  float* raw   = (float*)(ws + 746112);
  uint16_t* pT = (uint16_t*)(ws + 21717632);
  float* vpart = (float*)(ws + 30106240);
  float* csq   = (float*)(ws + 38494848);
  float* linv  = (float*)(ws + 38625920);
  float* gscl  = (float*)(ws + 38634112);

  hipLaunchKernelGGL(k0_prep,   dim3(160), dim3(256), 0, stream, clusters, cB);
  hipLaunchKernelGGL(k1_gemm1,  dim3(512), dim3(256), 0, stream, x, cB, raw, part);
  hipLaunchKernelGGL(k2_stats,  dim3(80),  dim3(64),  0, stream, part, gamma, beta, scsh, a_sum);
  hipLaunchKernelGGL(k3_bnsoft, dim3(1024),dim3(256), 0, stream, raw, scsh, pT, a_sum);
  hipLaunchKernelGGL(k4_gemm2,  dim3(512), dim3(256), 0, stream, x, pT, vpart);
  hipLaunchKernelGGL(k5a_ssq,   dim3(512), dim3(256), 0, stream, vpart, a_sum, clusters2, csq);
  hipLaunchKernelGGL(k5b_fin,   dim3(32),  dim3(64),  0, stream, csq, linv, gscl);
  hipLaunchKernelGGL(k5c_norm,  dim3(512), dim3(256), 0, stream, vpart, a_sum, clusters2, linv, gscl, out);
}